// Round 9
// baseline (3951.654 us; speedup 1.0000x reference)
//
#include <hip/hip_runtime.h>
#include <stdint.h>

#define NSTEPS 8
#define DT (1.0f / NSTEPS)

typedef __bf16 bfv8 __attribute__((ext_vector_type(8)));
typedef __bf16 bfv4 __attribute__((ext_vector_type(4)));
typedef float f32x4 __attribute__((ext_vector_type(4)));

static __device__ __forceinline__ float fast_tanh(float x) {
  float e = __expf(2.f * x);
  return 1.f - 2.f * __builtin_amdgcn_rcpf(e + 1.f);
}
static __device__ __forceinline__ f32x4 splat4(float v) {
  f32x4 r; r[0] = v; r[1] = v; r[2] = v; r[3] = v; return r;
}

// ---------------------------------------------------------------------------
// Per-slice weight blobs (bf16), 8 blobs x 73728 elems (147456 B each):
//   +0     W1s [2 kf][64 c][32]   = W1[k, s*64+c]        (k<64)
//   +4096  W2s [16 kf][64 c][32]  = W2[k, s*64+c]
//   +36864 Gts [16 kf][64 c][32]  = G[s*64+c, k],  G[j,k]=W2[j,k]*sum_m W1[m,j]W3[k,m]
//   +69632 W3s [8 kf][16 c][32]   = W3[(b&1)*256+k, (b>>1)*16+c]
// Within each 32-elem k-run, 8-elem group g stored at slot g ^ ((c>>1)&3)
// (bank de-conflict for ds_read_b128; reader XORs the same way).
// ---------------------------------------------------------------------------
__global__ __launch_bounds__(256) void pre_kernel(
    const float* __restrict__ W1, const float* __restrict__ W2,
    const float* __restrict__ W3, __bf16* __restrict__ blob,
    unsigned int* __restrict__ syncc) {
  int t = blockIdx.x * 256 + threadIdx.x;  // 73728
  if (t < 49152) syncc[t] = 0u;            // zero sync counters each launch
  if (t >= 73728) return;
  bfv8 o;
  int di;
  if (t < 4096) {  // W1
    int kq = t >> 9, colg = t & 511;
    int s = colg >> 6, c = colg & 63;
    int f = kq >> 2, gg = (kq & 3) ^ ((c >> 1) & 3);
    di = s * 73728 + f * 2048 + c * 32 + gg * 8;
#pragma unroll
    for (int e = 0; e < 8; ++e) o[e] = (__bf16)W1[(kq * 8 + e) * 512 + colg];
  } else if (t < 36864) {  // W2
    int u = t - 4096;
    int colg = u & 511, kc = u >> 9;
    int s = colg >> 6, c = colg & 63;
    int f = kc >> 2, gg = (kc & 3) ^ ((c >> 1) & 3);
    di = s * 73728 + 4096 + f * 2048 + c * 32 + gg * 8;
#pragma unroll
    for (int e = 0; e < 8; ++e) o[e] = (__bf16)W2[(kc * 8 + e) * 512 + colg];
  } else if (t < 69632) {  // Gt
    int u = t - 36864;
    int jg = u & 511, kc = u >> 9;
    float w1c[64];
#pragma unroll
    for (int m = 0; m < 64; ++m) w1c[m] = W1[m * 512 + jg];
    int s = jg >> 6, c = jg & 63;
    int f = kc >> 2, gg = (kc & 3) ^ ((c >> 1) & 3);
    di = s * 73728 + 36864 + f * 2048 + c * 32 + gg * 8;
#pragma unroll
    for (int e = 0; e < 8; ++e) {
      int k = kc * 8 + e;
      float sm = 0.f;
#pragma unroll
      for (int m = 0; m < 64; ++m) sm = fmaf(w1c[m], W3[k * 64 + m], sm);
      o[e] = (__bf16)(sm * W2[jg * 512 + k]);
    }
  } else {  // W3
    int u = t - 69632;
    int m = u & 63, kc = u >> 6;
    int tile = m >> 4, cm = m & 15;
    int b = tile * 2 + (kc >> 5);
    int f = (kc >> 2) & 7, gg = (kc & 3) ^ ((cm >> 1) & 3);
    di = b * 73728 + 69632 + f * 512 + cm * 32 + gg * 8;
#pragma unroll
    for (int e = 0; e < 8; ++e) o[e] = (__bf16)W3[(kc * 8 + e) * 64 + m];
  }
  *(bfv8*)(blob + di) = o;
}

// group sync: 8 blocks of a row-group rendezvous on one counter (used once).
static __device__ __forceinline__ void gsync(unsigned int* cnt, int tid) {
  __threadfence();
  __syncthreads();
  if (tid == 0) {
    __hip_atomic_fetch_add(cnt, 1u, __ATOMIC_RELEASE, __HIP_MEMORY_SCOPE_AGENT);
    int guard = 0;
    while (__hip_atomic_load(cnt, __ATOMIC_RELAXED, __HIP_MEMORY_SCOPE_AGENT) <
           8u) {
      __builtin_amdgcn_s_sleep(2);
      if (++guard > (1 << 22)) break;  // safety valve (diagnosable, no hang)
    }
    (void)__hip_atomic_load(cnt, __ATOMIC_ACQUIRE, __HIP_MEMORY_SCOPE_AGENT);
  }
  __syncthreads();
  __threadfence();
}

// ---------------------------------------------------------------------------
// Persistent integrator: 256 blocks = 32 row-groups x 8 col-slices,
// 256 threads (4 waves), 1 block/CU (LDS-forced) -> all co-resident.
// Weights LDS-resident; per-eval cross-block exchange of activations only.
// MFMA 16x16x32 bf16 (m89): A row=lane&15,k=(lane>>4)*8+i; B col=lane&15;
// D col=lane&15,row=(lane>>4)*4+reg.
// ---------------------------------------------------------------------------
__global__ __launch_bounds__(256, 1) void cnf_kernel(
    const float* __restrict__ x, const float* __restrict__ b1,
    const float* __restrict__ W1f, const float* __restrict__ b2,
    const float* __restrict__ b3, const __bf16* __restrict__ blob,
    char* __restrict__ actg, unsigned int* __restrict__ syncc,
    float* __restrict__ out) {
  __shared__ char wlds[147456];
  __shared__ char actv[8192];   // staged activation half [16 rows][256 k] swz
  __shared__ char xins[2048];   // [16][64] bf16 swz
  __shared__ float kxl[256];    // [16 rows][16 m]
  __shared__ float trl[16];

  const int tid = threadIdx.x;
  const int lane = tid & 63;
  const int w = tid >> 6;  // wave 0..3 = col-tile within slice
  const int lr = lane & 15;
  const int lq = lane >> 4;
  const int g = blockIdx.x & 31;   // row-group
  const int b = blockIdx.x >> 5;   // col-slice 0..7 (same-XCD peers if RR)
  const int rowbase = g * 16;

  // ---- stage weight blob -> LDS (linear; swizzle pre-baked) ----
  {
    const char* src = (const char*)blob + (size_t)b * 147456;
#pragma unroll 1
    for (int i = 0; i < 36; ++i) {
      const int off = (w * 36 + i) * 1024 + lane * 16;
      __builtin_amdgcn_global_load_lds(
          (const __attribute__((address_space(1))) uint32_t*)(src + off),
          (__attribute__((address_space(3))) uint32_t*)(wlds + off), 16, 0, 0);
    }
  }

  // per-lane constants
  const int colg = b * 64 + w * 16 + lr;  // global col of this lane's tiles
  const float b1c = b1[colg];
  const float w1tc = W1f[64 * 512 + colg];
  const float b2c = b2[colg];
  const float b3v = ((b & 1) == 0) ? b3[(b >> 1) * 16 + (tid & 15)] : 0.f;
  const int gx = lq ^ ((lr >> 1) & 3);
  const int bcol = (w * 16 + lr) * 64 + gx * 16;  // B-frag byte off in slab

  // group activity buffers (64 KB per group)
  char* gb = actg + (size_t)g * 65536;
  __bf16* h1buf = (__bf16*)gb;             // [16][512]
  __bf16* h2buf = (__bf16*)(gb + 16384);
  __bf16* vbuf = (__bf16*)(gb + 32768);
  float* kxbuf = (float*)(gb + 49152);     // [8 b][256]
  float* trbufg = (float*)(gb + 57344);    // [8 b][16]
  unsigned int* scg = syncc + g * 96 * 16;

  asm volatile("s_waitcnt vmcnt(0)" ::: "memory");
  __syncthreads();

  // replicated RK4 state: thread owns rows tid>>4, cols (tid&15)*4 ..+3
  const int srow = tid >> 4, scol = (tid & 15) * 4;
  float xb[4], ka[4];
  float ldv = 0.f, ldacc = 0.f;  // threads tid<16: row=tid

#define MFMA(A, Boff, C)                                                      \
  C = __builtin_amdgcn_mfma_f32_16x16x32_bf16(                                \
      A, *(const bfv8*)(wlds + (Boff)), C, 0, 0, 0)
#define AFRAG(c)                                                              \
  (*(const bfv8*)(actv + lr * 512 + ((((c) * 64) + lq * 16) ^ ((lr & 7) << 4))))
#define STAGE_ACT(SRCBUF, HF)                                                 \
  do {                                                                        \
    const int row_ = tid >> 4, ch_ = tid & 15;                                \
    bfv8 d0_ = *(const bfv8*)((SRCBUF) + row_ * 512 + (HF) * 256 + ch_ * 8);  \
    bfv8 d1_ =                                                                \
        *(const bfv8*)((SRCBUF) + row_ * 512 + (HF) * 256 + 128 + ch_ * 8);   \
    __syncthreads();                                                          \
    *(bfv8*)(actv + row_ * 512 + ((ch_ * 16) ^ ((row_ & 7) << 4))) = d0_;     \
    *(bfv8*)(actv + row_ * 512 + ((ch_ * 16 + 256) ^ ((row_ & 7) << 4))) =    \
        d1_;                                                                  \
    __syncthreads();                                                          \
  } while (0)

#pragma unroll 1
  for (int ev = 0; ev <= 4 * NSTEPS; ++ev) {
    // ---------------- combine (replicated, reads group kx/tr) -------------
    float xw[4];
    if (ev == 0) {
      const float* xr = x + (rowbase + srow) * 64 + scol;
#pragma unroll
      for (int i = 0; i < 4; ++i) { xb[i] = xr[i]; ka[i] = 0.f; xw[i] = xb[i]; }
    } else {
      const int gp = (ev - 1) & 3;
      const int tt = scol >> 4, cb2 = scol & 15;
      float kv[4];
#pragma unroll
      for (int i = 0; i < 4; ++i)
        kv[i] = kxbuf[(tt * 2) * 256 + srow * 16 + cb2 + i] +
                kxbuf[(tt * 2 + 1) * 256 + srow * 16 + cb2 + i];
      float tv = 0.f;
      if (tid < 16) {
#pragma unroll
        for (int bb = 0; bb < 8; ++bb) tv += trbufg[bb * 16 + tid];
      }
      if (gp < 3) {
        const float wg = (gp == 0) ? 1.f : 2.f;
        const float cn = (gp == 2) ? DT : 0.5f * DT;
#pragma unroll
        for (int i = 0; i < 4; ++i) {
          ka[i] += wg * kv[i];
          xw[i] = xb[i] + cn * kv[i];
        }
        if (tid < 16) ldacc += wg * tv;
      } else {
#pragma unroll
        for (int i = 0; i < 4; ++i) {
          xb[i] += (DT / 6.f) * (ka[i] + kv[i]);
          ka[i] = 0.f;
          xw[i] = xb[i];
        }
        if (tid < 16) { ldv -= (DT / 6.f) * (ldacc + tv); ldacc = 0.f; }
      }
    }
    if (ev == 4 * NSTEPS) {
      if (b == 0) {
        float* orow = out + (rowbase + srow) * 64 + scol;
#pragma unroll
        for (int i = 0; i < 4; ++i) orow[i] = xw[i];
        if (tid < 16) out[512 * 64 + rowbase + tid] = ldv;
      }
      break;
    }
    {
      bfv4 pk;
#pragma unroll
      for (int i = 0; i < 4; ++i) pk[i] = (__bf16)xw[i];
      *(bfv4*)(xins + srow * 128 + ((scol * 2) ^ ((srow & 7) << 4))) = pk;
    }
    __syncthreads();

    // ---------------- L1: h1 slice = tanh([xin,t] @ W1s + b1) -------------
    const int gq = ev & 3;
    const float tval =
        (ev >> 2) * DT + ((gq == 0) ? 0.f : (gq == 3) ? DT : 0.5f * DT);
    float ureg[4];
    {
      bfv8 a0 = *(const bfv8*)(xins + lr * 128 + ((lq * 16) ^ ((lr & 7) << 4)));
      bfv8 a1 =
          *(const bfv8*)(xins + lr * 128 + ((64 + lq * 16) ^ ((lr & 7) << 4)));
      f32x4 C = splat4(b1c + tval * w1tc);
      MFMA(a0, 0 * 4096 + bcol, C);
      MFMA(a1, 1 * 4096 + bcol, C);
#pragma unroll
      for (int r = 0; r < 4; ++r) {
        const float t1 = fast_tanh(C[r]);
        ureg[r] = 1.f - t1 * t1;
        h1buf[(lq * 4 + r) * 512 + colg] = (__bf16)t1;  // publish
      }
    }
    gsync(scg + (ev * 3 + 0) * 16, tid);

    // ---------------- L2: h2 slice = tanh(h1 @ W2s + b2) ------------------
    {
      f32x4 Ca = splat4(0.f), Cb = splat4(0.f);
#pragma unroll
      for (int hf = 0; hf < 2; ++hf) {
        STAGE_ACT(h1buf, hf);
#pragma unroll
        for (int c2 = 0; c2 < 4; ++c2) {
          const int c = c2 * 2, f = hf * 8 + c;
          bfv8 A0 = AFRAG(c), A1 = AFRAG(c + 1);
          MFMA(A0, 8192 + f * 4096 + bcol, Ca);
          MFMA(A1, 8192 + (f + 1) * 4096 + bcol, Cb);
        }
      }
#pragma unroll
      for (int r = 0; r < 4; ++r) {
        const float t2 = fast_tanh(Ca[r] + Cb[r] + b2c);
        h2buf[(lq * 4 + r) * 512 + colg] = (__bf16)t2;
        vbuf[(lq * 4 + r) * 512 + colg] = (__bf16)(1.f - t2 * t2);
      }
    }
    if (tid < 16) trl[tid] = 0.f;
    kxl[tid] = b3v;  // bias (half 0) or 0 (half 1)
    gsync(scg + (ev * 3 + 1) * 16, tid);

    // ---------------- TR: y = v @ Gts^T ; tr += sum u*y -------------------
    {
      f32x4 Ca = splat4(0.f), Cb = splat4(0.f);
#pragma unroll
      for (int hf = 0; hf < 2; ++hf) {
        STAGE_ACT(vbuf, hf);
#pragma unroll
        for (int c2 = 0; c2 < 4; ++c2) {
          const int c = c2 * 2, f = hf * 8 + c;
          bfv8 A0 = AFRAG(c), A1 = AFRAG(c + 1);
          MFMA(A0, 73728 + f * 4096 + bcol, Ca);
          MFMA(A1, 73728 + (f + 1) * 4096 + bcol, Cb);
        }
      }
      float pacc[4];
#pragma unroll
      for (int r = 0; r < 4; ++r) pacc[r] = (Ca[r] + Cb[r]) * ureg[r];
#pragma unroll
      for (int r = 0; r < 4; ++r) {
        pacc[r] += __shfl_xor(pacc[r], 1);
        pacc[r] += __shfl_xor(pacc[r], 2);
        pacc[r] += __shfl_xor(pacc[r], 4);
        pacc[r] += __shfl_xor(pacc[r], 8);
      }
      if (lr == 0) {
#pragma unroll
        for (int r = 0; r < 4; ++r) atomicAdd(&trl[lq * 4 + r], pacc[r]);
      }
    }

    // ---------------- L3: kx partial = h2[:,khalf] @ W3s ------------------
    {
      STAGE_ACT(h2buf, b & 1);
      f32x4 C3 = splat4(0.f);
      bfv8 A0 = AFRAG(2 * w), A1 = AFRAG(2 * w + 1);
      MFMA(A0, 139264 + (2 * w) * 1024 + lr * 64 + gx * 16, C3);
      MFMA(A1, 139264 + (2 * w + 1) * 1024 + lr * 64 + gx * 16, C3);
#pragma unroll
      for (int r = 0; r < 4; ++r)
        atomicAdd(&kxl[(lq * 4 + r) * 16 + lr], C3[r]);
    }
    __syncthreads();
    kxbuf[b * 256 + tid] = kxl[tid];          // publish kx partial
    if (tid < 16) trbufg[b * 16 + tid] = trl[tid];  // publish trace partial
    gsync(scg + (ev * 3 + 2) * 16, tid);
  }
#undef MFMA
#undef AFRAG
#undef STAGE_ACT
}

extern "C" void kernel_launch(void* const* d_in, const int* in_sizes, int n_in,
                              void* d_out, int out_size, void* d_ws,
                              size_t ws_size, hipStream_t stream) {
  const float* x = (const float*)d_in[0];
  const float* W1 = (const float*)d_in[1];
  const float* b1 = (const float*)d_in[2];
  const float* W2 = (const float*)d_in[3];
  const float* b2 = (const float*)d_in[4];
  const float* W3 = (const float*)d_in[5];
  const float* b3 = (const float*)d_in[6];
  float* out = (float*)d_out;

  __bf16* blob = (__bf16*)d_ws;                                   // 1.125 MB
  unsigned int* syncc = (unsigned int*)((char*)d_ws + 2097152);   // 192 KB
  char* actg = (char*)d_ws + 4194304;                             // 2 MB

  pre_kernel<<<288, 256, 0, stream>>>(W1, W2, W3, blob, syncc);
  cnf_kernel<<<256, 256, 0, stream>>>(x, b1, W1, b2, b3, blob, actg, syncc,
                                      out);
}

// Round 10
// 1123.983 us; speedup vs baseline: 3.5158x; 3.5158x over previous
//
#include <hip/hip_runtime.h>

#define NSTEPS 8
#define DT (1.0f / NSTEPS)

typedef __bf16 bfv8 __attribute__((ext_vector_type(8)));
typedef float f32x4 __attribute__((ext_vector_type(4)));

static __device__ __forceinline__ float fast_tanh(float x) {
  float e = __expf(2.f * x);
  return 1.f - 2.f * __builtin_amdgcn_rcpf(e + 1.f);
}

static __device__ __forceinline__ f32x4 splat4(float v) {
  f32x4 r; r[0] = v; r[1] = v; r[2] = v; r[3] = v; return r;
}

// ---------------------------------------------------------------------------
// Packed weight layouts (bf16), fragment-major for coalesced B-loads:
//  W1P[kq][512][8]  kq<8  : W1P[kq*4096+col*8+e] = W1[(kq*8+e)*512+col]
//  W2P[kc][512][8]  kc<64 : = W2[(kc*8+e)*512+col]
//  GtP[kc][512][8]  kc<64 : = G[j=col, k=kc*8+e],  G[j,k]=W2[j,k]*sum_i W1[i,j]W3[k,i]
//  W3P[kc][64][8]   kc<64 : = W3[(kc*8+e)*64+m]
// ---------------------------------------------------------------------------
__global__ __launch_bounds__(256) void pre_kernel(
    const float* __restrict__ W1, const float* __restrict__ W2,
    const float* __restrict__ W3, __bf16* __restrict__ W1P,
    __bf16* __restrict__ W2P, __bf16* __restrict__ GtP,
    __bf16* __restrict__ W3P) {
  int t = blockIdx.x * 256 + threadIdx.x;  // 73728 frags total
  if (t < 4096) {
    int kq = t >> 9, col = t & 511;
    bfv8 o;
#pragma unroll
    for (int e = 0; e < 8; ++e) o[e] = (__bf16)W1[(kq * 8 + e) * 512 + col];
    *(bfv8*)(W1P + t * 8) = o;
  } else if (t < 36864) {
    int g = t - 4096;
    int kc = g >> 9, col = g & 511;
    bfv8 o;
#pragma unroll
    for (int e = 0; e < 8; ++e) o[e] = (__bf16)W2[(kc * 8 + e) * 512 + col];
    *(bfv8*)(W2P + g * 8) = o;
  } else if (t < 69632) {
    int g = t - 36864;
    int kc = g >> 9, j = g & 511;
    float w1c[64];
#pragma unroll
    for (int m = 0; m < 64; ++m) w1c[m] = W1[m * 512 + j];
    bfv8 o;
#pragma unroll
    for (int e = 0; e < 8; ++e) {
      int k = kc * 8 + e;
      float s = 0.f;
#pragma unroll
      for (int m = 0; m < 64; ++m) s = fmaf(w1c[m], W3[k * 64 + m], s);
      o[e] = (__bf16)(s * W2[j * 512 + k]);
    }
    *(bfv8*)(GtP + g * 8) = o;
  } else if (t < 73728) {
    int g = t - 69632;
    int kc = g >> 6, m = g & 63;
    bfv8 o;
#pragma unroll
    for (int e = 0; e < 8; ++e) o[e] = (__bf16)W3[(kc * 8 + e) * 64 + m];
    *(bfv8*)(W3P + g * 8) = o;
  }
}

// ---------------------------------------------------------------------------
// Persistent integrator: 32 blocks x 16 rows, 8 waves.
// Per-block K-chunk ROTATION de-lockstep: block processes chunks in order
// (c+rot)&15 so the 4 CUs of an XCD never hit the same L2 lines at once.
// 8-deep register ring on the B-stream of the two 64-step phases.
// MFMA 16x16x32 bf16 (m89 mapping): A row=lane&15, k=(lane>>4)*8+i;
// B col=lane&15, same k; D col=lane&15, row=(lane>>4)*4+reg.
// Per eval: combine(reg) bar L1 bar L2 bar [TR ; L3(k-split all waves)] bar
// ---------------------------------------------------------------------------
__global__ __launch_bounds__(512, 2) void cnf_kernel(
    const float* __restrict__ x, const float* __restrict__ b1,
    const float* __restrict__ W1, const float* __restrict__ b2,
    const float* __restrict__ b3, const __bf16* __restrict__ W1P,
    const __bf16* __restrict__ W2P, const __bf16* __restrict__ GtP,
    const __bf16* __restrict__ W3P, float* __restrict__ out) {
  __shared__ __bf16 h1s[8192];  // [row][col] bytes, byte ^= (row&7)<<4
  __shared__ __bf16 h2s[8192];
  __shared__ __bf16 vs[8192];
  __shared__ __bf16 xins[1024];  // [16][64] plain
  __shared__ float kcur[1024];
  __shared__ float trbuf[16];

  const int tid = threadIdx.x;
  const int lane = tid & 63;
  const int w = tid >> 6;    // 0..7
  const int lr = lane & 15;
  const int lq = lane >> 4;
  const int rowbase = blockIdx.x * 16;
  // de-lockstep rotation: XCD-mates (bid = b, b+8, b+16, b+24 under RR)
  // get distinct chunk phases {r, r+9, r+2, r+11} mod 16.
  const int rot = (3 * blockIdx.x + (blockIdx.x >> 3)) & 15;
  const char* h1c = (const char*)h1s;
  const char* h2c = (const char*)h2s;
  const char* vsc = (const char*)vs;

  // hoisted per-lane constants (4 col-tiles per wave)
  float b1c[4], w1tc[4], b2c[4], b3c[4];
#pragma unroll
  for (int n = 0; n < 4; ++n) {
    const int col = (w * 4 + n) * 16 + lr;
    b1c[n] = b1[col];
    w1tc[n] = W1[64 * 512 + col];
    b2c[n] = b2[col];
    b3c[n] = b3[n * 16 + lr];
  }

  // per-thread RK4 state: elements tid and tid+512 of [16 rows][64]
  float xbA = 0.f, xbB = 0.f, kaA = 0.f, kaB = 0.f, ldv = 0.f, ldacc = 0.f;

#pragma unroll 1
  for (int ev = 0; ev <= 4 * NSTEPS; ++ev) {
    const int g = ev & 3;
    // ---------------- combine (per-thread registers) ----------------
    {
      float xwA, xwB;
      if (ev == 0) {
        xbA = x[rowbase * 64 + tid];
        xbB = x[rowbase * 64 + 512 + tid];
        xwA = xbA; xwB = xbB;
        kcur[tid] = 0.f; kcur[tid + 512] = 0.f;
        if (tid < 16) trbuf[tid] = 0.f;
      } else {
        const int gp = (ev - 1) & 3;
        const float k0 = kcur[tid], k1 = kcur[tid + 512];
        kcur[tid] = 0.f; kcur[tid + 512] = 0.f;
        float tv = 0.f;
        if (tid < 16) { tv = trbuf[tid]; trbuf[tid] = 0.f; }
        if (gp < 3) {
          const float wg = (gp == 0) ? 1.f : 2.f;
          const float cn = (gp == 2) ? DT : 0.5f * DT;
          kaA += wg * k0; kaB += wg * k1;
          xwA = xbA + cn * k0; xwB = xbB + cn * k1;
          if (tid < 16) ldacc += wg * tv;
        } else {
          xbA += (DT / 6.f) * (kaA + k0);
          xbB += (DT / 6.f) * (kaB + k1);
          kaA = 0.f; kaB = 0.f;
          xwA = xbA; xwB = xbB;
          if (tid < 16) { ldv -= (DT / 6.f) * (ldacc + tv); ldacc = 0.f; }
        }
      }
      if (ev == 4 * NSTEPS) {
        out[rowbase * 64 + tid] = xwA;
        out[rowbase * 64 + 512 + tid] = xwB;
        if (tid < 16) out[512 * 64 + rowbase + tid] = ldv;
        break;
      }
      xins[tid] = (__bf16)xwA;
      xins[tid + 512] = (__bf16)xwB;
    }
    __syncthreads();  // bar1

    // ---------------- L1: h1 = tanh([xin,t] @ W1 + b1) ----------------
    {
      const float tval =
          (ev >> 2) * DT + ((g == 0) ? 0.f : (g == 3) ? DT : 0.5f * DT);
      const bfv8 a0 = *(const bfv8*)&xins[lr * 64 + lq * 8];
      const bfv8 a1 = *(const bfv8*)&xins[lr * 64 + 32 + lq * 8];
      bfv8 ring[4];
#pragma unroll
      for (int p = 0; p < 4; ++p)
        ring[p] = *(const bfv8*)(W1P + ((p & 1) * 4 + lq) * 4096 +
                                 ((w * 4 + (p >> 1)) * 16 + lr) * 8);
      f32x4 C = splat4(0.f);
#pragma unroll
      for (int f = 0; f < 8; ++f) {
        const int n = f >> 1, h = f & 1;
        if (h == 0) C = splat4(b1c[n] + tval * w1tc[n]);
        C = __builtin_amdgcn_mfma_f32_16x16x32_bf16(h ? a1 : a0, ring[f & 3],
                                                    C, 0, 0, 0);
        if (f < 4) {
          const int f4 = f + 4;
          ring[f & 3] = *(const bfv8*)(W1P + ((f4 & 1) * 4 + lq) * 4096 +
                                       ((w * 4 + (f4 >> 1)) * 16 + lr) * 8);
        }
        if (h == 1) {
#pragma unroll
          for (int r = 0; r < 4; ++r) {
            const int row = lq * 4 + r;
            const int col = (w * 4 + n) * 16 + lr;
            *(__bf16*)((char*)h1s + row * 1024 +
                       ((col * 2) ^ ((row & 7) << 4))) = (__bf16)fast_tanh(C[r]);
          }
        }
      }
    }
    __syncthreads();  // bar2

    // ------- L2: h2 = tanh(h1 @ W2 + b2); v = 1-h2^2 (rot + ring-8) -------
    {
      bfv8 ring[8];
#pragma unroll
      for (int p = 0; p < 8; ++p) {
        const int cp = (p + rot) & 15;  // p < 8 -> tile 0
        ring[p] = *(const bfv8*)(W2P + (cp * 4 + lq) * 4096 +
                                 ((w * 4) * 16 + lr) * 8);
      }
      f32x4 C = splat4(0.f);
#pragma unroll
      for (int f = 0; f < 64; ++f) {
        const int c = f & 15, t = f >> 4;
        if (c == 0) C = splat4(0.f);
        const int cp = (c + rot) & 15;
        const bfv8 A = *(const bfv8*)(
            h1c + lr * 1024 + (((cp * 64) + lq * 16) ^ ((lr & 7) << 4)));
        C = __builtin_amdgcn_mfma_f32_16x16x32_bf16(A, ring[f & 7], C, 0, 0, 0);
        if (f < 56) {
          const int f8 = f + 8;
          const int cp8 = ((f8 & 15) + rot) & 15;
          ring[f & 7] =
              *(const bfv8*)(W2P + (cp8 * 4 + lq) * 4096 +
                             ((w * 4 + (f8 >> 4)) * 16 + lr) * 8);
        }
        if (c == 15) {
#pragma unroll
          for (int r = 0; r < 4; ++r) {
            const int row = lq * 4 + r;
            const int col = (w * 4 + t) * 16 + lr;
            const float tv = fast_tanh(C[r] + b2c[t]);
            const int bo = row * 1024 + ((col * 2) ^ ((row & 7) << 4));
            *(__bf16*)((char*)h2s + bo) = (__bf16)tv;
            *(__bf16*)((char*)vs + bo) = (__bf16)(1.f - tv * tv);
          }
        }
      }
    }
    __syncthreads();  // bar3

    // ------- TR: y = v @ G^T per j-tile; tr += sum_j u*y (rot + ring-8) ----
    {
      bfv8 ring[8];
#pragma unroll
      for (int p = 0; p < 8; ++p) {
        const int cp = (p + rot) & 15;
        ring[p] = *(const bfv8*)(GtP + (cp * 4 + lq) * 4096 +
                                 ((w * 4) * 16 + lr) * 8);
      }
      f32x4 C = splat4(0.f);
      float pacc[4] = {0.f, 0.f, 0.f, 0.f};
#pragma unroll
      for (int f = 0; f < 64; ++f) {
        const int c = f & 15, t = f >> 4;
        if (c == 0) C = splat4(0.f);
        const int cp = (c + rot) & 15;
        const bfv8 A = *(const bfv8*)(
            vsc + lr * 1024 + (((cp * 64) + lq * 16) ^ ((lr & 7) << 4)));
        C = __builtin_amdgcn_mfma_f32_16x16x32_bf16(A, ring[f & 7], C, 0, 0, 0);
        if (f < 56) {
          const int f8 = f + 8;
          const int cp8 = ((f8 & 15) + rot) & 15;
          ring[f & 7] =
              *(const bfv8*)(GtP + (cp8 * 4 + lq) * 4096 +
                             ((w * 4 + (f8 >> 4)) * 16 + lr) * 8);
        }
        if (c == 15) {
#pragma unroll
          for (int r = 0; r < 4; ++r) {
            const int row = lq * 4 + r;
            const int col = (w * 4 + t) * 16 + lr;
            const float h1v = (float)*(const __bf16*)(
                h1c + row * 1024 + ((col * 2) ^ ((row & 7) << 4)));
            pacc[r] += C[r] * (1.f - h1v * h1v);
          }
        }
      }
#pragma unroll
      for (int r = 0; r < 4; ++r) {
        float p = pacc[r];
        p += __shfl_xor(p, 1);
        p += __shfl_xor(p, 2);
        p += __shfl_xor(p, 4);
        p += __shfl_xor(p, 8);
        if (lr == 0) atomicAdd(&trbuf[lq * 4 + r], p);
      }
    }

    // ------- L3 (k-split across all 8 waves): kcur += h2[:,wk] @ W3[wk,:] ---
    {
      bfv8 A2[2];
#pragma unroll
      for (int h = 0; h < 2; ++h)
        A2[h] = *(const bfv8*)(h2c + lr * 1024 +
                               (((w * 128 + h * 64 + lq * 16)) ^
                                ((lr & 7) << 4)));
      bfv8 ring[4];
#pragma unroll
      for (int p = 0; p < 4; ++p)
        ring[p] = *(const bfv8*)(W3P + (w * 8 + (p & 1) * 4 + lq) * 512 +
                                 ((p >> 1) * 16 + lr) * 8);
      f32x4 C = splat4(0.f);
#pragma unroll
      for (int f = 0; f < 8; ++f) {
        const int mt = f >> 1, h = f & 1;
        if (h == 0) C = splat4((w == 0) ? b3c[mt] : 0.f);
        C = __builtin_amdgcn_mfma_f32_16x16x32_bf16(A2[h], ring[f & 3], C, 0,
                                                    0, 0);
        if (f < 4) {
          const int f4 = f + 4;
          ring[f & 3] =
              *(const bfv8*)(W3P + (w * 8 + (f4 & 1) * 4 + lq) * 512 +
                             ((f4 >> 1) * 16 + lr) * 8);
        }
        if (h == 1) {
#pragma unroll
          for (int r = 0; r < 4; ++r)
            atomicAdd(&kcur[(lq * 4 + r) * 64 + mt * 16 + lr], C[r]);
        }
      }
    }
    __syncthreads();  // bar4
  }
}

extern "C" void kernel_launch(void* const* d_in, const int* in_sizes, int n_in,
                              void* d_out, int out_size, void* d_ws,
                              size_t ws_size, hipStream_t stream) {
  const float* x = (const float*)d_in[0];
  const float* W1 = (const float*)d_in[1];
  const float* b1 = (const float*)d_in[2];
  const float* W2 = (const float*)d_in[3];
  const float* b2 = (const float*)d_in[4];
  const float* W3 = (const float*)d_in[5];
  const float* b3 = (const float*)d_in[6];
  float* out = (float*)d_out;
  __bf16* wsb = (__bf16*)d_ws;

  __bf16* W1P = wsb;            // 32768 elems
  __bf16* W2P = wsb + 32768;    // 262144
  __bf16* GtP = wsb + 294912;   // 262144
  __bf16* W3P = wsb + 557056;   // 32768

  pre_kernel<<<288, 256, 0, stream>>>(W1, W2, W3, W1P, W2P, GtP, W3P);
  cnf_kernel<<<32, 512, 0, stream>>>(x, b1, W1, b2, b3, W1P, W2P, GtP, W3P,
                                     out);
}

// Round 11
// 1021.960 us; speedup vs baseline: 3.8667x; 1.0998x over previous
//
#include <hip/hip_runtime.h>
#include <stdint.h>

#define NSTEPS 8
#define DT (1.0f / NSTEPS)

typedef __bf16 bfv8 __attribute__((ext_vector_type(8)));
typedef float f32x4 __attribute__((ext_vector_type(4)));

static __device__ __forceinline__ float fast_tanh(float x) {
  float e = __expf(2.f * x);
  return 1.f - 2.f * __builtin_amdgcn_rcpf(e + 1.f);
}

static __device__ __forceinline__ f32x4 splat4(float v) {
  f32x4 r; r[0] = v; r[1] = v; r[2] = v; r[3] = v; return r;
}

// ---------------------------------------------------------------------------
// Packed weight layouts (bf16), fragment-major for coalesced B-loads:
//  W1P[kq][512][8]  kq<8  : W1P[kq*4096+col*8+e] = W1[(kq*8+e)*512+col]
//  W2P[kc][512][8]  kc<64 : = W2[(kc*8+e)*512+col]
//  GtP[kc][512][8]  kc<64 : = G[j=col, k=kc*8+e],  G[j,k]=W2[j,k]*sum_i W1[i,j]W3[k,i]
//  W3P[kc][64][8]   kc<64 : = W3[(kc*8+e)*64+m]
// ---------------------------------------------------------------------------
__global__ __launch_bounds__(256) void pre_kernel(
    const float* __restrict__ W1, const float* __restrict__ W2,
    const float* __restrict__ W3, __bf16* __restrict__ W1P,
    __bf16* __restrict__ W2P, __bf16* __restrict__ GtP,
    __bf16* __restrict__ W3P) {
  int t = blockIdx.x * 256 + threadIdx.x;  // 73728 frags total
  if (t < 4096) {
    int kq = t >> 9, col = t & 511;
    bfv8 o;
#pragma unroll
    for (int e = 0; e < 8; ++e) o[e] = (__bf16)W1[(kq * 8 + e) * 512 + col];
    *(bfv8*)(W1P + t * 8) = o;
  } else if (t < 36864) {
    int g = t - 4096;
    int kc = g >> 9, col = g & 511;
    bfv8 o;
#pragma unroll
    for (int e = 0; e < 8; ++e) o[e] = (__bf16)W2[(kc * 8 + e) * 512 + col];
    *(bfv8*)(W2P + g * 8) = o;
  } else if (t < 69632) {
    int g = t - 36864;
    int kc = g >> 9, j = g & 511;
    float w1c[64];
#pragma unroll
    for (int m = 0; m < 64; ++m) w1c[m] = W1[m * 512 + j];
    bfv8 o;
#pragma unroll
    for (int e = 0; e < 8; ++e) {
      int k = kc * 8 + e;
      float s = 0.f;
#pragma unroll
      for (int m = 0; m < 64; ++m) s = fmaf(w1c[m], W3[k * 64 + m], s);
      o[e] = (__bf16)(s * W2[j * 512 + k]);
    }
    *(bfv8*)(GtP + g * 8) = o;
  } else if (t < 73728) {
    int g = t - 69632;
    int kc = g >> 6, m = g & 63;
    bfv8 o;
#pragma unroll
    for (int e = 0; e < 8; ++e) o[e] = (__bf16)W3[(kc * 8 + e) * 64 + m];
    *(bfv8*)(W3P + g * 8) = o;
  }
}

// ---------------------------------------------------------------------------
// Persistent integrator: 32 blocks x 16 rows, 8 waves.
// Residency plan (byte-cutting — per-CU L2 ingest is the measured wall):
//   registers: W2 k<256 (w2r[4][8], 128 VGPR/wave, static idx only)
//   LDS:       W3 (64KB, staged once)
//   streamed:  Gt 512KB + W2 k>=256 256KB + W1 64KB = 832KB/eval
// MFMA 16x16x32 bf16 (m89 mapping): A row=lane&15, k=(lane>>4)*8+i;
// B col=lane&15, same k; D col=lane&15, row=(lane>>4)*4+reg.
// Per eval: combine(reg) bar L1 bar L2(res+stream) bar [L3(LDS); TR(stream)] bar
// ---------------------------------------------------------------------------
__global__ __launch_bounds__(512, 2) void cnf_kernel(
    const float* __restrict__ x, const float* __restrict__ b1,
    const float* __restrict__ W1, const float* __restrict__ b2,
    const float* __restrict__ b3, const __bf16* __restrict__ W1P,
    const __bf16* __restrict__ W2P, const __bf16* __restrict__ GtP,
    const __bf16* __restrict__ W3P, float* __restrict__ out) {
  __shared__ char w3l[65536];    // W3P image, LDS-resident
  __shared__ __bf16 h1s[8192];   // [16][512], byte ^= (row&7)<<4
  __shared__ __bf16 h2s[8192];
  __shared__ __bf16 xins[1024];  // [16][64] plain
  __shared__ float kcur[1024];
  __shared__ float trbuf[16];

  const int tid = threadIdx.x;
  const int lane = tid & 63;
  const int w = tid >> 6;    // 0..7
  const int lr = lane & 15;
  const int lq = lane >> 4;
  const int rowbase = blockIdx.x * 16;
  const char* h1c = (const char*)h1s;
  const char* h2c = (const char*)h2s;

  // ---- stage W3 into LDS once (linear, 8 x 512thr x 16B) ----
  {
    const char* src = (const char*)W3P;
#pragma unroll
    for (int i = 0; i < 8; ++i)
      __builtin_amdgcn_global_load_lds(
          (const __attribute__((address_space(1))) uint32_t*)(src + i * 8192 +
                                                              tid * 16),
          (__attribute__((address_space(3))) uint32_t*)(w3l + i * 8192 +
                                                        tid * 16),
          16, 0, 0);
  }

  // hoisted per-lane constants (4 col-tiles per wave)
  float b1c[4], w1tc[4], b2c[4], b3c[4];
#pragma unroll
  for (int n = 0; n < 4; ++n) {
    const int col = (w * 4 + n) * 16 + lr;
    b1c[n] = b1[col];
    w1tc[n] = W1[64 * 512 + col];
    b2c[n] = b2[col];
    b3c[n] = b3[n * 16 + lr];
  }

  // ---- resident W2 lower half (k<256): 32 frags, statically indexed ----
  bfv8 w2r[4][8];
#pragma unroll
  for (int n = 0; n < 4; ++n) {
    const int cb = ((w * 4 + n) * 16 + lr) * 8;
#pragma unroll
    for (int c = 0; c < 8; ++c)
      w2r[n][c] = *(const bfv8*)(W2P + (c * 4 + lq) * 4096 + cb);
  }

  // per-thread RK4 state: elements tid and tid+512 of [16 rows][64]
  float xbA = 0.f, xbB = 0.f, kaA = 0.f, kaB = 0.f, ldv = 0.f, ldacc = 0.f;

  asm volatile("s_waitcnt vmcnt(0)" ::: "memory");  // W3 staging + w2r landed
  __syncthreads();

#pragma unroll 1
  for (int ev = 0; ev <= 4 * NSTEPS; ++ev) {
    const int g = ev & 3;
    // ---------------- combine (per-thread registers) ----------------
    {
      float xwA, xwB;
      if (ev == 0) {
        xbA = x[rowbase * 64 + tid];
        xbB = x[rowbase * 64 + 512 + tid];
        xwA = xbA; xwB = xbB;
        kcur[tid] = 0.f; kcur[tid + 512] = 0.f;
        if (tid < 16) trbuf[tid] = 0.f;
      } else {
        const int gp = (ev - 1) & 3;
        const float k0 = kcur[tid], k1 = kcur[tid + 512];
        kcur[tid] = 0.f; kcur[tid + 512] = 0.f;
        float tv = 0.f;
        if (tid < 16) { tv = trbuf[tid]; trbuf[tid] = 0.f; }
        if (gp < 3) {
          const float wg = (gp == 0) ? 1.f : 2.f;
          const float cn = (gp == 2) ? DT : 0.5f * DT;
          kaA += wg * k0; kaB += wg * k1;
          xwA = xbA + cn * k0; xwB = xbB + cn * k1;
          if (tid < 16) ldacc += wg * tv;
        } else {
          xbA += (DT / 6.f) * (kaA + k0);
          xbB += (DT / 6.f) * (kaB + k1);
          kaA = 0.f; kaB = 0.f;
          xwA = xbA; xwB = xbB;
          if (tid < 16) { ldv -= (DT / 6.f) * (ldacc + tv); ldacc = 0.f; }
        }
      }
      if (ev == 4 * NSTEPS) {
        out[rowbase * 64 + tid] = xwA;
        out[rowbase * 64 + 512 + tid] = xwB;
        if (tid < 16) out[512 * 64 + rowbase + tid] = ldv;
        break;
      }
      xins[tid] = (__bf16)xwA;
      xins[tid + 512] = (__bf16)xwB;
    }
    __syncthreads();  // bar1

    // ---------------- L1: h1 = tanh([xin,t] @ W1 + b1)  (W1 streamed) ------
    {
      const float tval =
          (ev >> 2) * DT + ((g == 0) ? 0.f : (g == 3) ? DT : 0.5f * DT);
      const bfv8 a0 = *(const bfv8*)&xins[lr * 64 + lq * 8];
      const bfv8 a1 = *(const bfv8*)&xins[lr * 64 + 32 + lq * 8];
#pragma unroll
      for (int n = 0; n < 4; ++n) {
        const int cb = ((w * 4 + n) * 16 + lr) * 8;
        f32x4 C = splat4(b1c[n] + tval * w1tc[n]);
        C = __builtin_amdgcn_mfma_f32_16x16x32_bf16(
            a0, *(const bfv8*)(W1P + lq * 4096 + cb), C, 0, 0, 0);
        C = __builtin_amdgcn_mfma_f32_16x16x32_bf16(
            a1, *(const bfv8*)(W1P + (4 + lq) * 4096 + cb), C, 0, 0, 0);
#pragma unroll
        for (int r = 0; r < 4; ++r) {
          const int row = lq * 4 + r;
          const int col = (w * 4 + n) * 16 + lr;
          *(__bf16*)((char*)h1s + row * 1024 +
                     ((col * 2) ^ ((row & 7) << 4))) = (__bf16)fast_tanh(C[r]);
        }
      }
    }
    __syncthreads();  // bar2

    // ------ L2: h2 = tanh(h1 @ W2 + b2); k<256 from regs, rest streamed ----
    {
      f32x4 C[4];
#pragma unroll
      for (int n = 0; n < 4; ++n) C[n] = splat4(0.f);
#pragma unroll
      for (int c = 0; c < 8; ++c) {  // resident half
        const bfv8 A = *(const bfv8*)(
            h1c + lr * 1024 + (((c * 64) + lq * 16) ^ ((lr & 7) << 4)));
#pragma unroll
        for (int n = 0; n < 4; ++n)
          C[n] = __builtin_amdgcn_mfma_f32_16x16x32_bf16(A, w2r[n][c], C[n],
                                                         0, 0, 0);
      }
#pragma unroll
      for (int c = 8; c < 16; ++c) {  // streamed half
        const bfv8 A = *(const bfv8*)(
            h1c + lr * 1024 + (((c * 64) + lq * 16) ^ ((lr & 7) << 4)));
#pragma unroll
        for (int n = 0; n < 4; ++n) {
          const bfv8 B = *(const bfv8*)(W2P + (c * 4 + lq) * 4096 +
                                        ((w * 4 + n) * 16 + lr) * 8);
          C[n] = __builtin_amdgcn_mfma_f32_16x16x32_bf16(A, B, C[n], 0, 0, 0);
        }
      }
#pragma unroll
      for (int n = 0; n < 4; ++n)
#pragma unroll
        for (int r = 0; r < 4; ++r) {
          const int row = lq * 4 + r;
          const int col = (w * 4 + n) * 16 + lr;
          const float tv = fast_tanh(C[n][r] + b2c[n]);
          *(__bf16*)((char*)h2s + row * 1024 + ((col * 2) ^ ((row & 7) << 4))) =
              (__bf16)tv;
        }
    }
    __syncthreads();  // bar3

    // ------- L3 (all-LDS): kcur += h2[:, k-chunk(w)] @ W3[k-chunk(w), :] ----
    {
      bfv8 A2[2];
#pragma unroll
      for (int h = 0; h < 2; ++h)
        A2[h] = *(const bfv8*)(h2c + lr * 1024 +
                               ((w * 128 + h * 64 + lq * 16) ^
                                ((lr & 7) << 4)));
      f32x4 C3 = splat4(0.f);
#pragma unroll
      for (int f = 0; f < 8; ++f) {
        const int mt = f >> 1, h = f & 1;
        if (h == 0) C3 = splat4((w == 0) ? b3c[mt] : 0.f);
        const bfv8 B = *(const bfv8*)(
            w3l + ((w * 8 + h * 4 + lq) * 512 + (mt * 16 + lr) * 8) * 2);
        C3 = __builtin_amdgcn_mfma_f32_16x16x32_bf16(A2[h], B, C3, 0, 0, 0);
        if (h == 1) {
#pragma unroll
          for (int r = 0; r < 4; ++r)
            atomicAdd(&kcur[(lq * 4 + r) * 64 + mt * 16 + lr], C3[r]);
        }
      }
    }

    // ------- TR (streamed): y = (1-h2^2) @ G^T; tr += sum_j u*y ------------
    {
      f32x4 C[4];
#pragma unroll
      for (int n = 0; n < 4; ++n) C[n] = splat4(0.f);
#pragma unroll
      for (int c = 0; c < 16; ++c) {
        const bfv8 hv = *(const bfv8*)(
            h2c + lr * 1024 + (((c * 64) + lq * 16) ^ ((lr & 7) << 4)));
        bfv8 av;
#pragma unroll
        for (int e = 0; e < 8; ++e) {
          const float t2 = (float)hv[e];
          av[e] = (__bf16)(1.f - t2 * t2);
        }
#pragma unroll
        for (int n = 0; n < 4; ++n) {
          const bfv8 B = *(const bfv8*)(GtP + (c * 4 + lq) * 4096 +
                                        ((w * 4 + n) * 16 + lr) * 8);
          C[n] = __builtin_amdgcn_mfma_f32_16x16x32_bf16(av, B, C[n], 0, 0, 0);
        }
      }
      float pacc[4] = {0.f, 0.f, 0.f, 0.f};
#pragma unroll
      for (int n = 0; n < 4; ++n)
#pragma unroll
        for (int r = 0; r < 4; ++r) {
          const int row = lq * 4 + r;
          const int col = (w * 4 + n) * 16 + lr;
          const float h1v = (float)*(const __bf16*)(
              h1c + row * 1024 + ((col * 2) ^ ((row & 7) << 4)));
          pacc[r] += C[n][r] * (1.f - h1v * h1v);
        }
#pragma unroll
      for (int r = 0; r < 4; ++r) {
        float p = pacc[r];
        p += __shfl_xor(p, 1);
        p += __shfl_xor(p, 2);
        p += __shfl_xor(p, 4);
        p += __shfl_xor(p, 8);
        if (lr == 0) atomicAdd(&trbuf[lq * 4 + r], p);
      }
    }
    __syncthreads();  // bar4
  }
}

extern "C" void kernel_launch(void* const* d_in, const int* in_sizes, int n_in,
                              void* d_out, int out_size, void* d_ws,
                              size_t ws_size, hipStream_t stream) {
  const float* x = (const float*)d_in[0];
  const float* W1 = (const float*)d_in[1];
  const float* b1 = (const float*)d_in[2];
  const float* W2 = (const float*)d_in[3];
  const float* b2 = (const float*)d_in[4];
  const float* W3 = (const float*)d_in[5];
  const float* b3 = (const float*)d_in[6];
  float* out = (float*)d_out;
  __bf16* wsb = (__bf16*)d_ws;

  __bf16* W1P = wsb;            // 32768 elems
  __bf16* W2P = wsb + 32768;    // 262144
  __bf16* GtP = wsb + 294912;   // 262144
  __bf16* W3P = wsb + 557056;   // 32768

  pre_kernel<<<288, 256, 0, stream>>>(W1, W2, W3, W1P, W2P, GtP, W3P);
  cnf_kernel<<<32, 512, 0, stream>>>(x, b1, W1, b2, b3, W1P, W2P, GtP, W3P,
                                     out);
}